// Round 1
// baseline (275.133 us; speedup 1.0000x reference)
//
#include <hip/hip_runtime.h>
#include <stdint.h>

#define N_ROWS 8192
#define D_DIM  1024
#define BK     64

typedef __attribute__((ext_vector_type(8))) __bf16 bf16x8;
typedef __attribute__((ext_vector_type(8))) short  short8;
typedef __attribute__((ext_vector_type(4))) float  f32x4;

#define GLD16(gptr, lptr) __builtin_amdgcn_global_load_lds( \
    (const __attribute__((address_space(1))) void*)(gptr),  \
    (__attribute__((address_space(3))) void*)(lptr), 16, 0, 0)

__device__ __forceinline__ unsigned short f2bf(float v) {
    unsigned int u = __float_as_uint(v);
    u += 0x7fffu + ((u >> 16) & 1u);   // RNE
    return (unsigned short)(u >> 16);
}

// fp32 -> bf16 convert, optional factor (logit_scale * log2(e)) folded in.
__global__ void convert_kernel(const float* __restrict__ src, short* __restrict__ dst,
                               const float* __restrict__ scale_p, int use_scale) {
    const float f = use_scale ? (*scale_p) * 1.44269504088896340736f : 1.0f;
    const size_t idx = ((size_t)blockIdx.x * 256 + threadIdx.x) * 8;
    float4 x0 = *(const float4*)(src + idx);
    float4 x1 = *(const float4*)(src + idx + 4);
    short8 o;
    o[0] = (short)f2bf(x0.x * f); o[1] = (short)f2bf(x0.y * f);
    o[2] = (short)f2bf(x0.z * f); o[3] = (short)f2bf(x0.w * f);
    o[4] = (short)f2bf(x1.x * f); o[5] = (short)f2bf(x1.y * f);
    o[6] = (short)f2bf(x1.z * f); o[7] = (short)f2bf(x1.w * f);
    *(short8*)(dst + idx) = o;
}

// 128x128 tile GEMM; epilogue: e = exp2(acc) (acc is already log2-space logits),
// reduce row sums + col sums in-wave, atomicAdd to global accumulators.
__global__ void gemm_exp_kernel(const short* __restrict__ A,   // img bf16, scaled
                                const short* __restrict__ B,   // txt bf16
                                float* __restrict__ row_sum,
                                float* __restrict__ col_sum) {
    __shared__ __align__(16) short As[128 * BK];
    __shared__ __align__(16) short Bs[128 * BK];

    const int tid  = threadIdx.x;
    const int lane = tid & 63;
    const int w    = tid >> 6;      // wave 0..3
    const int wr   = w >> 1;        // wave row (0..1)
    const int wc   = w & 1;         // wave col (0..1)
    const int ti   = blockIdx.y * 128;
    const int tj   = blockIdx.x * 128;

    const int quad = lane >> 4;
    const int l15  = lane & 15;

    // staging: lane -> (row-within-chunk, swizzled k-chunk)
    const int srow = lane >> 3;               // 0..7
    const int sg   = (lane & 7) ^ srow;       // global 16B k-chunk after XOR swizzle

    f32x4 acc[4][4];
#pragma unroll
    for (int i = 0; i < 4; i++)
#pragma unroll
        for (int j = 0; j < 4; j++) acc[i][j] = (f32x4){0.f, 0.f, 0.f, 0.f};

    const int arow = wr * 64 + l15;   // + fr*16  -> LDS row for a-frag
    const int brow = wc * 64 + l15;   // + fc*16  -> LDS row for b-frag

    for (int k0 = 0; k0 < D_DIM; k0 += BK) {
        // ---- stage A,B tiles (each wave: 4 chunks of 1KB per tile) ----
#pragma unroll
        for (int c = 0; c < 4; c++) {
            const int ch = w * 4 + c;             // 0..15, wave-uniform
            const int r  = ch * 8 + srow;         // tile row 0..127
            const short* ga = A + (size_t)(ti + r) * D_DIM + k0 + sg * 8;
            const short* gb = B + (size_t)(tj + r) * D_DIM + k0 + sg * 8;
            GLD16(ga, As + ch * 512);
            GLD16(gb, Bs + ch * 512);
        }
        __syncthreads();
        // ---- compute ----
#pragma unroll
        for (int kk = 0; kk < 2; kk++) {
            bf16x8 af[4], bfb[4];
#pragma unroll
            for (int fr = 0; fr < 4; fr++) {
                const int row = arow + fr * 16;
                const int kc  = ((kk << 2) + quad) ^ (row & 7);
                af[fr] = *(const bf16x8*)(As + row * BK + kc * 8);
            }
#pragma unroll
            for (int fc = 0; fc < 4; fc++) {
                const int row = brow + fc * 16;
                const int kc  = ((kk << 2) + quad) ^ (row & 7);
                bfb[fc] = *(const bf16x8*)(Bs + row * BK + kc * 8);
            }
#pragma unroll
            for (int fr = 0; fr < 4; fr++)
#pragma unroll
                for (int fc = 0; fc < 4; fc++)
                    acc[fr][fc] = __builtin_amdgcn_mfma_f32_16x16x32_bf16(
                        af[fr], bfb[fc], acc[fr][fc], 0, 0, 0);
        }
        __syncthreads();
    }

    // ---- epilogue: e = 2^acc, then row/col reductions ----
#pragma unroll
    for (int fr = 0; fr < 4; fr++)
#pragma unroll
        for (int fc = 0; fc < 4; fc++)
#pragma unroll
            for (int r = 0; r < 4; r++)
                acc[fr][fc][r] = __builtin_amdgcn_exp2f(acc[fr][fc][r]);

    // row sums: element (fr,fc,r) is logits[ti + wr*64 + fr*16 + quad*4 + r][tj + wc*64 + fc*16 + l15]
    const int rowbase = ti + wr * 64;
#pragma unroll
    for (int fr = 0; fr < 4; fr++) {
#pragma unroll
        for (int r = 0; r < 4; r++) {
            float s = acc[fr][0][r] + acc[fr][1][r] + acc[fr][2][r] + acc[fr][3][r];
            s += __shfl_xor(s, 1);
            s += __shfl_xor(s, 2);
            s += __shfl_xor(s, 4);
            s += __shfl_xor(s, 8);
            if (l15 == 0)
                atomicAdd(&row_sum[rowbase + fr * 16 + quad * 4 + r], s);
        }
    }

    // col sums
    const int colbase = tj + wc * 64;
#pragma unroll
    for (int fc = 0; fc < 4; fc++) {
        float s = 0.f;
#pragma unroll
        for (int fr = 0; fr < 4; fr++)
#pragma unroll
            for (int r = 0; r < 4; r++) s += acc[fr][fc][r];
        s += __shfl_xor(s, 16);
        s += __shfl_xor(s, 32);
        if (quad == 0)
            atomicAdd(&col_sum[colbase + fc * 16 + l15], s);
    }
}

// exact fp32 diagonal: diag[i] = scale * dot(img[i], txt[i])
__global__ void diag_kernel(const float* __restrict__ img, const float* __restrict__ txt,
                            const float* __restrict__ scale_p, float* __restrict__ diag) {
    const int w    = threadIdx.x >> 6;
    const int lane = threadIdx.x & 63;
    const int row  = blockIdx.x * 4 + w;
    const float4* a = (const float4*)(img + (size_t)row * D_DIM);
    const float4* b = (const float4*)(txt + (size_t)row * D_DIM);
    float s = 0.f;
#pragma unroll
    for (int c = lane; c < D_DIM / 4; c += 64) {
        float4 x = a[c], y = b[c];
        s += x.x * y.x + x.y * y.y + x.z * y.z + x.w * y.w;
    }
#pragma unroll
    for (int m = 1; m < 64; m <<= 1) s += __shfl_xor(s, m);
    if (lane == 0) diag[row] = s * (*scale_p);
}

__global__ void finish_kernel(const float* __restrict__ rs, const float* __restrict__ cs,
                              const float* __restrict__ diag, float* __restrict__ out) {
    const int tid  = threadIdx.x;
    const int lane = tid & 63;
    const int w    = tid >> 6;
    float s = 0.f;
    for (int i = tid; i < N_ROWS; i += 256)
        s += logf(rs[i]) + logf(cs[i]) - 2.0f * diag[i];
#pragma unroll
    for (int m = 1; m < 64; m <<= 1) s += __shfl_xor(s, m);
    __shared__ float wsum[4];
    if (lane == 0) wsum[w] = s;
    __syncthreads();
    if (tid == 0)
        out[0] = (wsum[0] + wsum[1] + wsum[2] + wsum[3]) * (0.5f / (float)N_ROWS);
}

extern "C" void kernel_launch(void* const* d_in, const int* in_sizes, int n_in,
                              void* d_out, int out_size, void* d_ws, size_t ws_size,
                              hipStream_t stream) {
    const float* img     = (const float*)d_in[0];
    const float* txt     = (const float*)d_in[1];
    const float* scale_p = (const float*)d_in[2];
    float* out = (float*)d_out;

    char* ws = (char*)d_ws;
    short* imgbf   = (short*)ws;                                  // 16 MB
    short* txtbf   = (short*)(ws + (size_t)16 * 1024 * 1024);     // 16 MB
    float* row_sum = (float*)(ws + (size_t)32 * 1024 * 1024);     // 32 KB
    float* col_sum = row_sum + N_ROWS;                            // 32 KB
    float* diag    = col_sum + N_ROWS;                            // 32 KB

    hipMemsetAsync(row_sum, 0, 2 * N_ROWS * sizeof(float), stream);

    convert_kernel<<<4096, 256, 0, stream>>>(img, imgbf, scale_p, 1);
    convert_kernel<<<4096, 256, 0, stream>>>(txt, txtbf, scale_p, 0);

    dim3 grid(N_ROWS / 128, N_ROWS / 128);
    gemm_exp_kernel<<<grid, 256, 0, stream>>>(imgbf, txtbf, row_sum, col_sum);

    diag_kernel<<<N_ROWS / 4, 256, 0, stream>>>(img, txt, scale_p, diag);
    finish_kernel<<<1, 256, 0, stream>>>(row_sum, col_sum, diag, out);
}